// Round 5
// baseline (85.305 us; speedup 1.0000x reference)
//
#include <hip/hip_runtime.h>
#include <float.h>

// Chamfer distance, B=8, N1=N2=4096, 3-D fp32 points.
// dist(a,b) = |a|^2 + |b|^2 - 2 a.b ; min over the other set, both directions.
// Packed dual-FP32 inner loop, per (2 B-points x 1 A-point):
//   3 v_pk_fma_f32 + 1 v_min3_f32 = 2.0 VALU instr per pair.
// Cross-block combine via uint atomicMin into 256 KB L2-resident array.
// Final reduction fused via last-block-done trick (counter init 0xFFFFFFFF
// by the same 0xFF memset that inits the mins array).

typedef float v2f __attribute__((ext_vector_type(2)));

#define NBATCH 8
#define NPTS   4096
#define BLK    256
#define PTS    16                 // A-points per thread
#define NCHUNK 32
#define CHUNK  (NPTS / NCHUNK)    // 128 B-points staged per block
#define PAIRS  (CHUNK / 2)        // 64 packed pairs
#define NSLOTS (2 * NBATCH * NPTS)  // 65536 A-slots
#define NBLOCKS (2 * NBATCH * NCHUNK)  // 512

__global__ __launch_bounds__(BLK)
void chamfer_fused_kernel(const float* __restrict__ p1,
                          const float* __restrict__ p2,
                          unsigned int* __restrict__ mins /* [2][8][4096] uint bits */,
                          unsigned int* __restrict__ counter,
                          float* __restrict__ out)
{
    // Packed-pair B staging: sXY[p] = {x0,x1,y0,y1}, sZW[p] = {z0,z1,w0,w1}
    // (w = |b|^2). All lanes read the same address -> LDS broadcast.
    __shared__ float4 sXY[PAIRS];
    __shared__ float4 sZW[PAIRS];
    __shared__ int    sIsLast;

    int bid   = blockIdx.x;
    int chunk = bid & (NCHUNK - 1);  bid >>= 5;   // 32 chunks
    int b     = bid & (NBATCH - 1);  bid >>= 3;   // 8 batches
    int dir   = bid;                              // 0 or 1

    const float* A    = dir ? p2 : p1;
    const float* Bpts = dir ? p1 : p2;
    int tid = threadIdx.x;

    if (tid < PAIRS) {
        const float* s = Bpts + ((size_t)b * NPTS + chunk * CHUNK + 2 * tid) * 3;
        float x0 = s[0], y0 = s[1], z0 = s[2];
        float x1 = s[3], y1 = s[4], z1 = s[5];
        sXY[tid] = make_float4(x0, x1, y0, y1);
        sZW[tid] = make_float4(z0, z1,
                               x0 * x0 + y0 * y0 + z0 * z0,
                               x1 * x1 + y1 * y1 + z1 * z1);
    }

    // Per-thread A-points, pre-scaled by -2, duplicated into packed pairs.
    v2f  m2x[PTS], m2y[PTS], m2z[PTS];
    float n1[PTS], best[PTS];
#pragma unroll
    for (int k = 0; k < PTS; ++k) {
        const float* s = A + ((size_t)b * NPTS + tid + k * BLK) * 3;
        float x = s[0], y = s[1], z = s[2];
        float mx = -2.0f * x, my = -2.0f * y, mz = -2.0f * z;
        m2x[k] = (v2f){mx, mx};
        m2y[k] = (v2f){my, my};
        m2z[k] = (v2f){mz, mz};
        n1[k]  = x * x + y * y + z * z;
        best[k] = FLT_MAX;
    }
    __syncthreads();

    // Min-scan: per packed B-pair, per A-point: 3 pk_fma + 1 min3.
#pragma unroll 2
    for (int p = 0; p < PAIRS; ++p) {
        float4 xy = sXY[p];
        float4 zw = sZW[p];
        v2f qx = (v2f){xy.x, xy.y};
        v2f qy = (v2f){xy.z, xy.w};
        v2f qz = (v2f){zw.x, zw.y};
        v2f qw = (v2f){zw.z, zw.w};
#pragma unroll
        for (int k = 0; k < PTS; ++k) {
            v2f t = __builtin_elementwise_fma(m2x[k], qx, qw);
            t = __builtin_elementwise_fma(m2y[k], qy, t);
            t = __builtin_elementwise_fma(m2z[k], qz, t);
            best[k] = fminf(best[k], fminf(t.x, t.y));   // -> v_min3_f32
        }
    }

    // Publish per-A-point chunk-min via uint atomicMin (valid for d >= 0;
    // init 0xFFFFFFFF > bit pattern of any finite positive float).
    unsigned int* marr = mins + ((size_t)dir * NBATCH + b) * NPTS + tid;
#pragma unroll
    for (int k = 0; k < PTS; ++k) {
        float d = fmaxf(best[k] + n1[k], 0.0f);
        atomicMin(&marr[k * BLK], __float_as_uint(d));
    }

    // Last-block-done: counter was memset to 0xFFFFFFFF; the k-th arrival's
    // atomicAdd returns k-2 (mod 2^32), so the 512th sees 510.
    __syncthreads();
    if (tid == 0) {
        __threadfence();                       // release our atomicMins
        unsigned int old = atomicAdd(counter, 1u);
        sIsLast = (old == (unsigned int)(NBLOCKS - 2));
    }
    __syncthreads();
    if (!sIsLast) return;

    // Final reduction by the last block: read mins through L2 (agent-scope
    // atomic loads -- L1 may hold stale lines from a previous graph replay).
    __threadfence();                           // acquire
    float sum = 0.0f;
#pragma unroll
    for (int j = 0; j < NSLOTS / BLK; ++j) {
        unsigned int u = __hip_atomic_load(&mins[tid + j * BLK],
                                           __ATOMIC_RELAXED,
                                           __HIP_MEMORY_SCOPE_AGENT);
        sum += __uint_as_float(u);
    }
#pragma unroll
    for (int off = 32; off > 0; off >>= 1)
        sum += __shfl_down(sum, off, 64);
    __shared__ float wsum[4];
    int wave = tid >> 6;
    if ((tid & 63) == 0) wsum[wave] = sum;
    __syncthreads();
    if (tid == 0)
        out[0] = (wsum[0] + wsum[1] + wsum[2] + wsum[3]) /
                 (float)(NBATCH * NPTS);
}

extern "C" void kernel_launch(void* const* d_in, const int* in_sizes, int n_in,
                              void* d_out, int out_size, void* d_ws, size_t ws_size,
                              hipStream_t stream) {
    const float* p1 = (const float*)d_in[0];
    const float* p2 = (const float*)d_in[1];
    float* out = (float*)d_out;
    unsigned int* mins = (unsigned int*)d_ws;
    unsigned int* counter = mins + NSLOTS;

    // One memset, pattern 0xFF: inits mins to 0xFFFFFFFF (uint-max sentinel)
    // AND the completion counter to 0xFFFFFFFF (see arrival arithmetic above).
    hipMemsetAsync(d_ws, 0xFF, (size_t)(NSLOTS + 1) * sizeof(unsigned int), stream);

    chamfer_fused_kernel<<<NBLOCKS, BLK, 0, stream>>>(p1, p2, mins, counter, out);
}

// Round 6
// 82.009 us; speedup vs baseline: 1.0402x; 1.0402x over previous
//
#include <hip/hip_runtime.h>
#include <float.h>

// Chamfer distance, B=8, N1=N2=4096, 3-D fp32 points.
// dist(a,b) = |a|^2 + |b|^2 - 2 a.b ; min over the other set, both directions.
// Packed dual-FP32 inner loop, per (2 B-points x 1 A-point):
//   3 v_pk_fma_f32 + 1 v_min3_f32 = 2.0 VALU instr per pair.
// Cross-block combine via uint atomicMin into 256 KB L2-resident array.
//
// Measured floor analysis (R2-R5): total dur_us 81-86 across four structural
// variants; ~40 us is the harness's 256 MB d_ws poison fill (memory-bound at
// ~83% HBM peak), ~30 us replay/restore overhead outside our dispatches,
// ~10 us our kernels (VALU floor ~7 us). This variant was the best measured.

typedef float v2f __attribute__((ext_vector_type(2)));

#define NBATCH 8
#define NPTS   4096
#define BLK    256
#define PTS    16                 // A-points per thread
#define NCHUNK 32
#define CHUNK  (NPTS / NCHUNK)    // 128 B-points staged per block
#define PAIRS  (CHUNK / 2)        // 64 packed pairs

__global__ __launch_bounds__(BLK)
void chamfer_min_kernel(const float* __restrict__ p1,
                        const float* __restrict__ p2,
                        unsigned int* __restrict__ mins /* [2][8][4096] uint bits */)
{
    // Packed-pair B staging: sXY[p] = {x0,x1,y0,y1}, sZW[p] = {z0,z1,w0,w1}
    // (w = |b|^2). All lanes read the same address -> LDS broadcast.
    __shared__ float4 sXY[PAIRS];
    __shared__ float4 sZW[PAIRS];

    int bid   = blockIdx.x;
    int chunk = bid & (NCHUNK - 1);  bid >>= 5;   // 32 chunks
    int b     = bid & (NBATCH - 1);  bid >>= 3;   // 8 batches
    int dir   = bid;                              // 0 or 1

    const float* A    = dir ? p2 : p1;
    const float* Bpts = dir ? p1 : p2;
    int tid = threadIdx.x;

    if (tid < PAIRS) {
        const float* s = Bpts + ((size_t)b * NPTS + chunk * CHUNK + 2 * tid) * 3;
        float x0 = s[0], y0 = s[1], z0 = s[2];
        float x1 = s[3], y1 = s[4], z1 = s[5];
        sXY[tid] = make_float4(x0, x1, y0, y1);
        sZW[tid] = make_float4(z0, z1,
                               x0 * x0 + y0 * y0 + z0 * z0,
                               x1 * x1 + y1 * y1 + z1 * z1);
    }

    // Per-thread A-points, pre-scaled by -2, duplicated into packed pairs.
    v2f  m2x[PTS], m2y[PTS], m2z[PTS];
    float n1[PTS], best[PTS];
#pragma unroll
    for (int k = 0; k < PTS; ++k) {
        const float* s = A + ((size_t)b * NPTS + tid + k * BLK) * 3;
        float x = s[0], y = s[1], z = s[2];
        float mx = -2.0f * x, my = -2.0f * y, mz = -2.0f * z;
        m2x[k] = (v2f){mx, mx};
        m2y[k] = (v2f){my, my};
        m2z[k] = (v2f){mz, mz};
        n1[k]  = x * x + y * y + z * z;
        best[k] = FLT_MAX;
    }
    __syncthreads();

    // Min-scan: per packed B-pair, per A-point: 3 pk_fma + 1 min3.
#pragma unroll 2
    for (int p = 0; p < PAIRS; ++p) {
        float4 xy = sXY[p];
        float4 zw = sZW[p];
        v2f qx = (v2f){xy.x, xy.y};
        v2f qy = (v2f){xy.z, xy.w};
        v2f qz = (v2f){zw.x, zw.y};
        v2f qw = (v2f){zw.z, zw.w};
#pragma unroll
        for (int k = 0; k < PTS; ++k) {
            v2f t = __builtin_elementwise_fma(m2x[k], qx, qw);
            t = __builtin_elementwise_fma(m2y[k], qy, t);
            t = __builtin_elementwise_fma(m2z[k], qz, t);
            best[k] = fminf(best[k], fminf(t.x, t.y));   // -> v_min3_f32
        }
    }

    // Publish per-A-point chunk-min via uint atomicMin (valid for d >= 0).
    unsigned int* marr = mins + ((size_t)dir * NBATCH + b) * NPTS + tid;
#pragma unroll
    for (int k = 0; k < PTS; ++k) {
        float d = fmaxf(best[k] + n1[k], 0.0f);
        atomicMin(&marr[k * BLK], __float_as_uint(d));
    }
}

__global__ __launch_bounds__(1024)
void chamfer_reduce_kernel(const float* __restrict__ mins, float* __restrict__ out)
{
    // Sum 2*8*4096 = 65536 min-distances; loss = sum / (8*4096).
    __shared__ float wave_sums[16];
    const float4* m4 = (const float4*)mins;
    float s = 0.0f;
#pragma unroll
    for (int i = 0; i < 16; ++i) {
        float4 v = m4[threadIdx.x + i * 1024];
        s += (v.x + v.y) + (v.z + v.w);
    }
#pragma unroll
    for (int off = 32; off > 0; off >>= 1)
        s += __shfl_down(s, off, 64);
    int wave = threadIdx.x >> 6;
    if ((threadIdx.x & 63) == 0) wave_sums[wave] = s;
    __syncthreads();
    if (threadIdx.x < 16) {
        s = wave_sums[threadIdx.x];
#pragma unroll
        for (int off = 8; off > 0; off >>= 1)
            s += __shfl_down(s, off, 16);
        if (threadIdx.x == 0) out[0] = s / (float)(NBATCH * NPTS);
    }
}

extern "C" void kernel_launch(void* const* d_in, const int* in_sizes, int n_in,
                              void* d_out, int out_size, void* d_ws, size_t ws_size,
                              hipStream_t stream) {
    const float* p1 = (const float*)d_in[0];
    const float* p2 = (const float*)d_in[1];
    float* out = (float*)d_out;
    unsigned int* mins = (unsigned int*)d_ws;

    // Init mins to 0xFFFFFFFF (uint max; > any positive float bit pattern).
    hipMemsetAsync(d_ws, 0xFF, (size_t)2 * NBATCH * NPTS * sizeof(unsigned int), stream);

    int nblocks = 2 * NBATCH * NCHUNK;  // 512
    chamfer_min_kernel<<<nblocks, BLK, 0, stream>>>(p1, p2, mins);
    chamfer_reduce_kernel<<<1, 1024, 0, stream>>>((const float*)d_ws, out);
}